// Round 5
// baseline (653.655 us; speedup 1.0000x reference)
//
#include <hip/hip_runtime.h>
#include <hip/hip_bf16.h>
#include <stdint.h>
#include <stddef.h>

// Inputs/outputs fp32. Weights converted once to bf16; GEMMs bf16 MFMA fp32 acc.
// R5 changes vs R4 (620 us): feed-bound theory (per-CU front-door ~10-14 B/cyc
// is the invariant wall across R2-R4 schedules).
//  - gemm_p3 v2: BOTH A and B LDS streams 3-deep; vmcnt(NI) only ever waits on
//    loads issued a FULL K-step earlier (R4's vmcnt(1) waited on B issued ~154cy
//    before). A32 reg-staging dropped: X staged fp32 via global_load_lds into a
//    swizzled fp32 tile, cvt_pk to bf16 at fragment-read time.
//  - MODE5 BN=512 (gx=2): halves the fp32 X re-read (front door 1.07GB -> ~0.8GB).
//  - Mids (MODE2/4) BN=256, same 3-deep loop, 2 blocks/CU.

using u16 = unsigned short;
using u32 = unsigned int;

__device__ __forceinline__ float u2f(u16 u) {
  union { unsigned i; float f; } c; c.i = ((unsigned)u) << 16; return c.f;
}
__device__ __forceinline__ u16 f2u(float f) {
  __hip_bfloat16 h = __float2bfloat16(f);          // RNE
  union { __hip_bfloat16 h; u16 u; } c; c.h = h; return c.u;
}
__device__ __forceinline__ u32 pk2(float lo, float hi) {
  __hip_bfloat162 h = __float22bfloat162_rn(make_float2(lo, hi));
  union { __hip_bfloat162 h; u32 u; } c; c.h = h; return c.u;
}
__device__ __forceinline__ float sigm(float x) { return 1.f / (1.f + expf(-x)); }

typedef __attribute__((ext_vector_type(8))) short bfrag;   // 8 bf16 = 4 VGPRs
typedef __attribute__((ext_vector_type(4))) float f32x4;

__device__ __forceinline__ void gl_lds16(const u16* g, u16* l) {
  __builtin_amdgcn_global_load_lds((const __attribute__((address_space(1))) void*)g,
                                   (__attribute__((address_space(3))) void*)l,
                                   16, 0, 0);
}

// ---- batched fp32 -> bf16 weight conversion (17 segments, 1 launch) ----
#define NSEG 17
struct CvtArgs {
  const float* src[NSEG];
  u16* dst[NSEG];
  int cum[NSEG + 1];
};
__global__ __launch_bounds__(256) void cvt_multi(CvtArgs a, int total) {
  int i = blockIdx.x * 256 + threadIdx.x;
  if (i >= total) return;
  int s = 0;
  while (s + 1 < NSEG && i >= a.cum[s + 1]) ++s;
  const int off = i - a.cum[s];
  a.dst[s][off] = f2u(a.src[s][off]);
}

// ============================================================================
// gemm_p3 v2: BM=128, BN={256,512}, BK=32. C = epilogue(A @ W^T).
// 512 thr, 8 waves (2M x 4N), wave = 64 x BN/4. 3-deep A + 3-deep B LDS.
// vmcnt never waits on the K-step just issued. K=512 assumed (16 steps).
// MODE 2: atomicAdd(pred[row], sum_col relu(acc+bias[col])*wlo[col])
// MODE 4: outb = bf16(relu(sigm(pred[row])*acc + bias[col]))
// MODE 5 (BN=512): bx==0 -> ubuf-add relu into outb; bx==1 -> W2/bias into outb2
// ============================================================================
template <int MODE, bool A32, int BN>
__global__ __launch_bounds__(512, (BN == 512) ? 2 : 4)
void gemm_p3(const void* __restrict__ Av, int lda, size_t abase,
             const u16* __restrict__ W, int ldw, int K,
             const u16* __restrict__ bias,
             const float* __restrict__ ubuf,
             const u16* __restrict__ wlo,
             float* __restrict__ pred,
             u16* __restrict__ outb, int ldc,
             const u16* __restrict__ W2, int ldw2, u16* __restrict__ outb2)
{
  constexpr int ABU = A32 ? 8192 : 4096;          // u16 units per A buf (fp32/bf16)
  constexpr int BBU = BN * 32;                    // u16 units per B buf
  constexpr int NT  = BN / 64;                    // B frag count per wave
  constexpr int NBC = BN / 128;                   // B gl_lds chunks per thread
  constexpr int NI  = (A32 ? 2 : 1) + NBC;        // VMEM instrs/thread/K-step
  constexpr int STG = 3 * ABU + 3 * BBU;
  constexpr int EPI = (MODE == 2) ? 0 : 128 * (BN + 8);
  constexpr int SMU = (STG > EPI) ? STG : EPI;
  __shared__ u16 smem[SMU];
  u16* const Bbase = smem + 3 * ABU;

  const int tid  = threadIdx.x;
  const int wave = tid >> 6, lane = tid & 63;
  const int wr = wave >> 2, wc = wave & 3;        // 2M x 4N
  const int quad = lane >> 4, l16 = lane & 15;

  // T1 bijective XCD swizzle (nwg % 8 == 0 in all uses); consecutive flats on
  // one XCD traverse bx-fastest -> X slab L2-reused across bx.
  const int gx = gridDim.x;
  const int nwg = gx * gridDim.y;
  int flat = blockIdx.y * gx + blockIdx.x;
  if ((nwg & 7) == 0) { const int q = nwg >> 3; flat = (flat & 7) * q + (flat >> 3); }
  const int bx = flat % gx;
  const int by = flat / gx;

  const int row0 = by * 128;
  const bool isM = (MODE != 5) || (bx == 0);
  const int col0 = (MODE == 5) ? 0 : bx * BN;
  const u16* Wp  = (MODE == 5 && !isM) ? W2  : W;
  const int ldwp = (MODE == 5 && !isM) ? ldw2 : ldw;

  f32x4 acc[4][NT];
#pragma unroll
  for (int i = 0; i < 4; i++)
#pragma unroll
    for (int j = 0; j < NT; j++)
#pragma unroll
      for (int r = 0; r < 4; r++) acc[i][j][r] = 0.f;

  // --- staging: linear LDS dest (gl_lds requirement), inverse-swizzled source ---
  auto stageA = [&](int k0, u16* Ab) {
    if constexpr (A32) {
      // fp32 tile 128x32: 1024 16B-chunks, 2/thread. 8 chunks/row, swz cc^(row&7)
#pragma unroll
      for (int p = 0; p < 2; p++) {
        const int c = p * 512 + tid, row = c >> 3, cc = c & 7;
        const float* g = (const float*)Av + (abase + (size_t)(row0 + row)) * lda
                         + k0 + ((cc ^ (row & 7)) << 2);
        gl_lds16((const u16*)g, Ab + c * 8);
      }
    } else {
      // bf16 tile 128x32: 512 chunks, 1/thread. 4 chunks/row, swz cb^((row>>1)&3)
      const int c = tid, row = c >> 2, cb = c & 3;
      gl_lds16((const u16*)Av + (abase + (size_t)(row0 + row)) * lda
               + k0 + ((cb ^ ((row >> 1) & 3)) << 3),
               Ab + c * 8);
    }
  };
  auto stageB = [&](int k0, u16* Bb) {
#pragma unroll
    for (int p = 0; p < NBC; p++) {
      const int c = p * 512 + tid, row = c >> 2, cb = c & 3;
      gl_lds16(Wp + (size_t)(col0 + row) * ldwp + k0 + ((cb ^ ((row >> 1) & 3)) << 3),
               Bb + c * 8);
    }
  };

  auto compute = [&](const u16* Ab_, const u16* Bb_) {
    bfrag af[4], bf[NT];
    if constexpr (A32) {
      const float* Af = (const float*)Ab_;
#pragma unroll
      for (int mt = 0; mt < 4; mt++) {
        const int R = wr * 64 + mt * 16 + l16;
        const int c0 = ((quad * 2)     ^ (R & 7)) << 2;
        const int c1 = ((quad * 2 + 1) ^ (R & 7)) << 2;
        f32x4 x0 = *(const f32x4*)(Af + R * 32 + c0);
        f32x4 x1 = *(const f32x4*)(Af + R * 32 + c1);
        uint4 u4;
        u4.x = pk2(x0[0], x0[1]); u4.y = pk2(x0[2], x0[3]);
        u4.z = pk2(x1[0], x1[1]); u4.w = pk2(x1[2], x1[3]);
        af[mt] = *(const bfrag*)&u4;
      }
    } else {
#pragma unroll
      for (int mt = 0; mt < 4; mt++) {
        const int R = wr * 64 + mt * 16 + l16;
        af[mt] = *(const bfrag*)(Ab_ + R * 32 + ((quad ^ ((R >> 1) & 3)) << 3));
      }
    }
#pragma unroll
    for (int nt = 0; nt < NT; nt++) {
      const int R = wc * (BN / 4) + nt * 16 + l16;
      bf[nt] = *(const bfrag*)(Bb_ + R * 32 + ((quad ^ ((R >> 1) & 3)) << 3));
    }
    __builtin_amdgcn_s_setprio(1);
#pragma unroll
    for (int mt = 0; mt < 4; mt++)
#pragma unroll
      for (int nt = 0; nt < NT; nt++)
        acc[mt][nt] = __builtin_amdgcn_mfma_f32_16x16x32_bf16(af[mt], bf[nt], acc[mt][nt], 0, 0, 0);
    __builtin_amdgcn_s_setprio(0);
  };

  const int nt_ = K >> 5;                          // 16 for K=512

  // ---- prologue: stage steps 0 and 1 (step-1 loads stay in flight) ----
  stageA(0, smem);                 stageB(0, Bbase);
  stageA(32, smem + ABU);          stageB(32, Bbase + BBU);
  if constexpr (NI == 6) asm volatile("s_waitcnt vmcnt(6)" ::: "memory");
  else                   asm volatile("s_waitcnt vmcnt(3)" ::: "memory");
  __builtin_amdgcn_sched_barrier(0);
  __builtin_amdgcn_s_barrier();

  // ---- main loop: issue t+2, compute t, wait leaving t+2 in flight ----
  for (int t = 0; t < nt_; ++t) {
    if (t + 2 < nt_) {
      const int s = (t + 2) % 3;
      stageA((t + 2) << 5, smem + s * ABU);
      stageB((t + 2) << 5, Bbase + s * BBU);
    }
    compute(smem + (t % 3) * ABU, Bbase + (t % 3) * BBU);
    if (t + 2 < nt_) {
      if constexpr (NI == 6) asm volatile("s_waitcnt vmcnt(6)" ::: "memory");
      else                   asm volatile("s_waitcnt vmcnt(3)" ::: "memory");
    } else if (t + 1 < nt_) {
      asm volatile("s_waitcnt vmcnt(0)" ::: "memory");
    }
    __builtin_amdgcn_sched_barrier(0);
    if (t + 1 < nt_) __builtin_amdgcn_s_barrier();
  }

  // C/D layout (m89/m91): col = lane&15, row = quad*4 + reg
  if constexpr (MODE == 2) {
#pragma unroll
    for (int mt = 0; mt < 4; mt++) {
#pragma unroll
      for (int r = 0; r < 4; r++) {
        const int rg = row0 + wr * 64 + mt * 16 + quad * 4 + r;
        float s = 0.f;
#pragma unroll
        for (int nt = 0; nt < NT; nt++) {
          const int cg = col0 + wc * (BN / 4) + nt * 16 + l16;
          float v = acc[mt][nt][r] + u2f(bias[cg]);
          v = fmaxf(v, 0.f);
          s += v * u2f(wlo[cg]);
        }
#pragma unroll
        for (int off = 1; off < 16; off <<= 1) s += __shfl_xor(s, off, 16);
        if (l16 == 0) atomicAdd(pred + rg, s);
      }
    }
  } else {
    // bf16 out via LDS tile [128][BN+8] for coalesced 16B stores
    u16* outp = (MODE == 5 && !isM) ? outb2 : outb;
    u16* tile = smem;
    __syncthreads();                               // K-loop fully done
#pragma unroll
    for (int mt = 0; mt < 4; mt++)
#pragma unroll
      for (int nt = 0; nt < NT; nt++)
#pragma unroll
        for (int r = 0; r < 4; r++) {
          const int lrow = wr * 64 + mt * 16 + quad * 4 + r;
          const int lcol = wc * (BN / 4) + nt * 16 + l16;
          const int rg = row0 + lrow;
          const int cg = col0 + lcol;
          float v = acc[mt][nt][r];
          if (MODE == 5 && isM) {
            const size_t grow = (size_t)rg;        // abase==0 here
            const int urow = (int)(((grow >> 12) << 6) | (grow & 63));   // b*64+w
            v += ubuf[(size_t)urow * 512 + cg];
            v = fmaxf(v, 0.f);
          } else if (MODE == 5) {
            v += u2f(bias[cg]);
            v = fmaxf(v, 0.f);
          } else {                                 // MODE 4
            v = sigm(pred[rg]) * v + u2f(bias[cg]);
            v = fmaxf(v, 0.f);
          }
          tile[lrow * (BN + 8) + lcol] = f2u(v);
        }
    __syncthreads();
    const int row = tid >> 2, cst = (tid & 3) * (BN / 4);
    const u16* src = tile + row * (BN + 8) + cst;
    u16* dst = outp + (size_t)(row0 + row) * ldc + col0 + cst;
#pragma unroll
    for (int j = 0; j < BN / 32; j++)
      *(uint4*)(dst + j * 8) = *(const uint4*)(src + j * 8);
  }
}

// ============================================================================
// 128x128-tile GEMM (R2-proven) — small GEMMs + !big fallback path.
// ============================================================================
template <int MODE, bool A32>
__global__ __launch_bounds__(256)
void gemm_bt(const void* __restrict__ Av, int lda, size_t abase,
             const u16* __restrict__ W, int ldw, int K,
             const u16* __restrict__ bias,
             const float* __restrict__ ubuf,
             const u16* __restrict__ wlo,
             float* __restrict__ pred,
             u16* __restrict__ outb,
             float* __restrict__ outf,
             int ldc,
             const u16* __restrict__ W2, int ldw2, u16* __restrict__ outb2)
{
  __shared__ u16 smem[32768];
  u16* const Abase = smem;
  u16* const Bbase = smem + 16384;

  const int tid  = threadIdx.x;
  const int wave = tid >> 6, lane = tid & 63;
  const int wr = wave >> 1, wc = wave & 1;
  const int quad = lane >> 4, l16 = lane & 15;
  const int srow8 = lane >> 3;
  const int scolsw = ((lane & 7) ^ srow8) * 8;

  const int gx = gridDim.x;
  const int nwg = gx * gridDim.y;
  int flat = blockIdx.y * gx + blockIdx.x;
  if ((nwg & 7) == 0) { const int q = nwg >> 3; flat = (flat & 7) * q + (flat >> 3); }
  const int bx = flat % gx;
  const int by = flat / gx;

  const int row0 = by * 128;
  const bool isM = (MODE != 5) || (bx < 4);
  const int col0 = (MODE == 5 ? (bx & 3) : bx) * 128;
  const u16* Wp  = (MODE == 5 && !isM) ? W2  : W;
  const int ldwp = (MODE == 5 && !isM) ? ldw2 : ldw;

  f32x4 acc[4][4];
#pragma unroll
  for (int i = 0; i < 4; i++)
#pragma unroll
    for (int j = 0; j < 4; j++)
#pragma unroll
      for (int r = 0; r < 4; r++) acc[i][j][r] = 0.f;

  float4 rf[8];
  uint4  ra[4];

  auto stageA = [&](int kk0, u16* dst) {
#pragma unroll
    for (int i = 0; i < 4; i++) {
      const int chunk = wave * 4 + i;
      gl_lds16((const u16*)Av + (abase + (size_t)(row0 + chunk * 8 + srow8)) * lda + kk0 + scolsw,
               dst + chunk * 512 + lane * 8);
    }
  };
  auto stageB = [&](int kk0, u16* dst) {
#pragma unroll
    for (int i = 0; i < 4; i++) {
      const int chunk = wave * 4 + i;
      gl_lds16(Wp + (size_t)(col0 + chunk * 8 + srow8) * ldwp + kk0 + scolsw,
               dst + chunk * 512 + lane * 8);
    }
  };
  auto loadRF = [&](int kk0) {
#pragma unroll
    for (int i = 0; i < 4; i++) {
      const int idx = i * 256 + tid, sr = idx >> 3, sc = (idx & 7) * 8;
      const float* p = (const float*)Av + (abase + (size_t)(row0 + sr)) * lda + kk0 + sc;
      rf[2 * i]     = *(const float4*)p;
      rf[2 * i + 1] = *(const float4*)(p + 4);
    }
  };
  auto convRA = [&]() {
#pragma unroll
    for (int i = 0; i < 4; i++) {
      ra[i].x = pk2(rf[2 * i].x, rf[2 * i].y);
      ra[i].y = pk2(rf[2 * i].z, rf[2 * i].w);
      ra[i].z = pk2(rf[2 * i + 1].x, rf[2 * i + 1].y);
      ra[i].w = pk2(rf[2 * i + 1].z, rf[2 * i + 1].w);
    }
  };
  auto writeA = [&](u16* dst) {
#pragma unroll
    for (int i = 0; i < 4; i++) {
      const int idx = i * 256 + tid, sr = idx >> 3, cb = idx & 7;
      *(uint4*)(dst + sr * 64 + ((cb ^ (sr & 7)) << 3)) = ra[i];
    }
  };
  auto compute = [&](const u16* Ac, const u16* Bc) {
#pragma unroll
    for (int kk = 0; kk < 64; kk += 32) {
      const int cb0 = (kk >> 3) + quad;
      const int cbsw = ((cb0 ^ (l16 & 7)) << 3);
      bfrag af[4], bf[4];
#pragma unroll
      for (int mt = 0; mt < 4; mt++) {
        const int R = wr * 64 + mt * 16 + l16;
        af[mt] = *(const bfrag*)(Ac + R * 64 + cbsw);
      }
#pragma unroll
      for (int nt2 = 0; nt2 < 4; nt2++) {
        const int R = wc * 64 + nt2 * 16 + l16;
        bf[nt2] = *(const bfrag*)(Bc + R * 64 + cbsw);
      }
#pragma unroll
      for (int mt = 0; mt < 4; mt++)
#pragma unroll
        for (int nt2 = 0; nt2 < 4; nt2++)
          acc[mt][nt2] = __builtin_amdgcn_mfma_f32_16x16x32_bf16(af[mt], bf[nt2], acc[mt][nt2], 0, 0, 0);
    }
  };

  const int ntile = K >> 6;
  int cur = 0;

  if constexpr (A32) {
    loadRF(0); convRA(); writeA(Abase);
    stageB(0, Bbase);
    if (ntile > 1) loadRF(64);
  } else {
    stageA(0, Abase);
    stageB(0, Bbase);
  }
  __syncthreads();

  for (int t = 0; t < ntile; ++t) {
    const bool more = (t + 1 < ntile);
    u16* Ac = Abase + cur * 8192;
    u16* Bc = Bbase + cur * 8192;
    u16* An = Abase + (cur ^ 1) * 8192;
    u16* Bn = Bbase + (cur ^ 1) * 8192;
    if (more) {
      if constexpr (!A32) stageA((t + 1) << 6, An);
      stageB((t + 1) << 6, Bn);
      if constexpr (A32) {
        convRA(); writeA(An);
        if (t + 2 < ntile) loadRF((t + 2) << 6);
      }
    }
    compute(Ac, Bc);
    __syncthreads();
    cur ^= 1;
  }

  if constexpr (MODE == 2) {
#pragma unroll
    for (int mt = 0; mt < 4; mt++) {
#pragma unroll
      for (int r = 0; r < 4; r++) {
        const int rg = row0 + wr * 64 + mt * 16 + quad * 4 + r;
        float s = 0.f;
#pragma unroll
        for (int nt = 0; nt < 4; nt++) {
          const int cg = col0 + wc * 64 + nt * 16 + l16;
          float v = acc[mt][nt][r] + u2f(bias[cg]);
          v = fmaxf(v, 0.f);
          s += v * u2f(wlo[cg]);
        }
#pragma unroll
        for (int off = 1; off < 16; off <<= 1) s += __shfl_xor(s, off, 16);
        if (l16 == 0) atomicAdd(pred + rg, s);
      }
    }
  } else if constexpr (MODE == 3) {
#pragma unroll
    for (int mt = 0; mt < 4; mt++)
#pragma unroll
      for (int nt = 0; nt < 4; nt++)
#pragma unroll
        for (int r = 0; r < 4; r++) {
          const int rg = row0 + wr * 64 + mt * 16 + quad * 4 + r;
          const int cg = col0 + wc * 64 + nt * 16 + l16;
          outf[(size_t)rg * ldc + cg] = acc[mt][nt][r] + u2f(bias[cg]);
        }
  } else {
    u16* tile = smem;                    // 128 x 136
    u16* outp = (MODE == 5 && !isM) ? outb2 : outb;
    __syncthreads();
#pragma unroll
    for (int mt = 0; mt < 4; mt++)
#pragma unroll
      for (int nt = 0; nt < 4; nt++)
#pragma unroll
        for (int r = 0; r < 4; r++) {
          const int lrow = wr * 64 + mt * 16 + quad * 4 + r;
          const int lcol = wc * 64 + nt * 16 + l16;
          const int rg = row0 + lrow;
          const int cg = col0 + lcol;
          float v = acc[mt][nt][r];
          if (MODE == 0 || (MODE == 5 && isM)) {
            const size_t grow = abase + rg;
            const int urow = (int)(((grow >> 12) << 6) | (grow & 63));
            v += ubuf[(size_t)urow * 512 + cg];
            v = fmaxf(v, 0.f);
          } else if (MODE == 1 || MODE == 5) {
            v += u2f(bias[cg]);
            v = fmaxf(v, 0.f);
          } else {  // MODE 4
            v = sigm(pred[rg]) * v + u2f(bias[cg]);
            v = fmaxf(v, 0.f);
          }
          tile[lrow * 136 + lcol] = f2u(v);
        }
    __syncthreads();
    const int row = tid >> 1, half = tid & 1;
    const u16* src = tile + row * 136 + half * 64;
    u16* dst = outp + (size_t)(row0 + row) * ldc + col0 + half * 64;
#pragma unroll
    for (int j = 0; j < 8; j++)
      *(uint4*)(dst + j * 8) = *(const uint4*)(src + j * 8);
  }
}

__global__ void fill_kernel(float* __restrict__ p, const u16* __restrict__ val, int n) {
  int i = blockIdx.x * blockDim.x + threadIdx.x;
  if (i < n) p[i] = u2f(*val);
}

__global__ void adj_out_kernel(const float* __restrict__ r, float* __restrict__ out) {
  int i = blockIdx.x * 256 + threadIdx.x;            // (b,v,w)
  int b = i >> 12, v = (i >> 6) & 63, w = i & 63;
  out[i] = r[(b << 12) + (w << 6) + v];              // pred_adj[b,v,w] = r[b,w,v]
}

__global__ __launch_bounds__(512)
void msum_kernel(const float* __restrict__ r, const u16* __restrict__ M, u16* __restrict__ x) {
  const int bv = blockIdx.x;                          // b*64+v
  const int b = bv >> 6, v = bv & 63;
  __shared__ float s[64];
  if (threadIdx.x < 64) {
    const int w = threadIdx.x;
    s[w] = sigm(r[(b << 12) + (w << 6) + v]);
  }
  __syncthreads();
  const int m = threadIdx.x;                          // channel 0..511
  const u16* Mp = M + (((size_t)(b << 12) + (v << 6)) << 9) + m;
  float acc = 0.f;
#pragma unroll 8
  for (int w = 0; w < 64; w++) acc += s[w] * u2f(Mp[(size_t)w << 9]);
  x[(size_t)bv * 512 + m] = f2u(acc);
}

__global__ __launch_bounds__(256)
void gru_kernel(const float* __restrict__ gi, const float* __restrict__ gh,
                const u16* __restrict__ h, float* __restrict__ hn) {
  int i = blockIdx.x * 256 + threadIdx.x;             // 1024*512
  int row = i >> 9, d = i & 511;
  const float* gir = gi + (size_t)row * 1536;
  const float* ghr = gh + (size_t)row * 1536;
  float rr = sigm(gir[d] + ghr[d]);
  float z  = sigm(gir[512 + d] + ghr[512 + d]);
  float n  = tanhf(gir[1024 + d] + rr * ghr[1024 + d]);
  float hv = u2f(h[i]);
  hn[i] = (1.f - z) * n + z * hv;
}

__global__ __launch_bounds__(256)
void readout_kernel(const float* __restrict__ hn,
                    const u16* __restrict__ Wr1, const u16* __restrict__ br1,
                    const u16* __restrict__ Wr2, const u16* __restrict__ br2,
                    float* __restrict__ out) {
  const int row = blockIdx.x;
  __shared__ float hrow[512];
  for (int d = threadIdx.x; d < 512; d += 256) hrow[d] = hn[(size_t)row * 512 + d];
  __syncthreads();
  const int wave = threadIdx.x >> 6, lane = threadIdx.x & 63;
  for (int j = wave; j < 28; j += 4) {
    const u16* wrow;
    float bias;
    size_t off;
    if (j < 26) { wrow = Wr1 + (size_t)j * 512; bias = u2f(br1[j]); off = 65536 + (size_t)row * 26 + j; }
    else { int jj = j - 26; wrow = Wr2 + (size_t)jj * 512; bias = u2f(br2[jj]); off = 92160 + (size_t)row * 2 + jj; }
    float s = 0.f;
    for (int d = lane; d < 512; d += 64) s += hrow[d] * u2f(wrow[d]);
#pragma unroll
    for (int o = 32; o; o >>= 1) s += __shfl_down(s, o);
    if (lane == 0) out[off] = s + bias;
  }
}

extern "C" void kernel_launch(void* const* d_in, const int* in_sizes, int n_in,
                              void* d_out, int out_size, void* d_ws, size_t ws_size,
                              hipStream_t stream)
{
  (void)in_sizes; (void)n_in; (void)out_size;
  const void*  X  = d_in[0];                 // edge_features [16,64,64,512] fp32
  char* ws = (char*)d_ws;

  const bool big = (ws_size >= 158905344ULL);   // full-H1 fused path needs ~151.5 MiB

  // ---- workspace layouts ----
  u16 *Mb, *H1, *xb, *nfb, *Wmb, *bmb, *Wl1b, *bl1b, *Wl2b, *bl2b, *Wlob, *blob;
  u16 *Wihb, *bihb, *Whhb, *bhhb, *Wr1b, *br1b, *Wr2b, *br2b;
  float *pred1, *rbuf, *ubuf, *gi, *gh, *hn;
  if (big) {
    Mb    = (u16*)(ws);                         // 64 MB  M bf16 [65536,512]
    H1    = (u16*)(ws + 67108864);              // 64 MB  link hidden, full
    pred1 = (float*)(ws + 134217728);           // 256 KB
    rbuf  = (float*)(ws + 134479872);           // 256 KB
    ubuf  = (float*)(ws + 134742016);           // 2 MB
    xb    = (u16*)(ws + 136839168);             // 1 MB
    gi    = (float*)(ws + 137887744);           // 6 MB
    gh    = (float*)(ws + 144179200);           // 6 MB
    hn    = (float*)(ws + 150470656);           // 2 MB
    nfb   = (u16*)(ws + 152567808);
    Wmb   = (u16*)(ws + 153616384);
    bmb   = (u16*)(ws + 154664960);
    Wl1b  = (u16*)(ws + 154665984);
    bl1b  = (u16*)(ws + 155190272);
    Wl2b  = (u16*)(ws + 155191296);
    bl2b  = (u16*)(ws + 155715584);
    Wlob  = (u16*)(ws + 155716608);
    blob  = (u16*)(ws + 155717632);
    Wihb  = (u16*)(ws + 155718656);
    bihb  = (u16*)(ws + 157291520);
    Whhb  = (u16*)(ws + 157295616);
    bhhb  = (u16*)(ws + 158868480);
    Wr1b  = (u16*)(ws + 158872576);
    br1b  = (u16*)(ws + 158901248);
    Wr2b  = (u16*)(ws + 158902272);
    br2b  = (u16*)(ws + 158904320);
  } else {                                      // quartered fallback layout
    Mb    = (u16*)(ws);
    H1    = (u16*)(ws + 67108864);
    pred1 = (float*)(ws + 83886080);
    rbuf  = (float*)(ws + 84148224);
    ubuf  = (float*)(ws + 84410368);
    xb    = (u16*)(ws + 86507520);
    gi    = (float*)(ws + 87556096);
    gh    = (float*)(ws + 93847552);
    hn    = (float*)(ws + 100139008);
    nfb   = (u16*)(ws + 102236416);
    Wmb   = (u16*)(ws + 103284992);
    bmb   = (u16*)(ws + 104333568);
    Wl1b  = (u16*)(ws + 104334592);
    bl1b  = (u16*)(ws + 104858880);
    Wl2b  = (u16*)(ws + 104859904);
    bl2b  = (u16*)(ws + 105384192);
    Wlob  = (u16*)(ws + 105385216);
    blob  = (u16*)(ws + 105386240);
    Wihb  = (u16*)(ws + 105387264);
    bihb  = (u16*)(ws + 106960128);
    Whhb  = (u16*)(ws + 106964224);
    bhhb  = (u16*)(ws + 108537088);
    Wr1b  = (u16*)(ws + 108541184);
    br1b  = (u16*)(ws + 108573952);
    Wr2b  = (u16*)(ws + 108574976);
    br2b  = (u16*)(ws + 108579072);
  }

  float* out = (float*)d_out;

  // batched weight conversion (1 launch)
  {
    CvtArgs ca;
    const int seg_in[NSEG]  = {1,4,5,6,7,8,9,10,11,12,13,14,15,16,17,18,19};
    u16* seg_dst[NSEG] = {nfb,Wmb,bmb,Wl1b,bl1b,Wl2b,bl2b,Wlob,blob,
                          Wihb,bihb,Whhb,bhhb,Wr1b,br1b,Wr2b,br2b};
    const int seg_n[NSEG] = {524288,524288,512,262144,512,262144,512,512,1,
                             786432,1536,786432,1536,13312,26,1024,2};
    int total = 0;
    for (int s = 0; s < NSEG; s++) {
      ca.src[s] = (const float*)d_in[seg_in[s]];
      ca.dst[s] = seg_dst[s];
      ca.cum[s] = total;
      total += seg_n[s];
    }
    ca.cum[NSEG] = total;
    cvt_multi<<<(total + 255) / 256, 256, 0, stream>>>(ca, total);
  }

  // u = nf @ Wm[:, :512]^T + bm  (fp32)
  gemm_bt<3, false><<<dim3(4, 8), 256, 0, stream>>>(nfb, 512, 0, Wmb, 1024, 512, bmb,
      nullptr, nullptr, nullptr, nullptr, ubuf, 512, nullptr, 0, nullptr);
  // pred1 & rbuf (contiguous 131072 floats) = blo
  fill_kernel<<<512, 256, 0, stream>>>(pred1, blob, 131072);

  if (big) {
    // fused: [Mb | H1] = relu(X @ [Wm_e | Wl1]^T + [u | bl1]), BN=512
    gemm_p3<5, true, 512><<<dim3(2, 512), 512, 0, stream>>>(X, 512, 0, Wmb + 512, 1024, 512,
        bl1b, ubuf, nullptr, nullptr, Mb, 512, Wl1b, 512, H1);
    // pred1 += sum relu(H1 @ Wl2^T + bl2) * Wlo
    gemm_p3<2, false, 256><<<dim3(2, 512), 512, 0, stream>>>(H1, 512, 0, Wl2b, 512, 512, bl2b,
        nullptr, Wlob, pred1, nullptr, 512, nullptr, 0, nullptr);
    // H1 = relu(sigm(pred1) * M @ Wl1^T + bl1)
    gemm_p3<4, false, 256><<<dim3(2, 512), 512, 0, stream>>>(Mb, 512, 0, Wl1b, 512, 512, bl1b,
        nullptr, nullptr, pred1, H1, 512, nullptr, 0, nullptr);
    gemm_p3<2, false, 256><<<dim3(2, 512), 512, 0, stream>>>(H1, 512, 0, Wl2b, 512, 512, bl2b,
        nullptr, Wlob, rbuf, nullptr, 512, nullptr, 0, nullptr);
  } else {
    gemm_bt<0, true><<<dim3(4, 512), 256, 0, stream>>>(X, 512, 0, Wmb + 512, 1024, 512,
        nullptr, ubuf, nullptr, nullptr, Mb, nullptr, 512, nullptr, 0, nullptr);
    for (int q = 0; q < 4; q++) {
      const size_t ro = (size_t)q * 16384;
      gemm_bt<1, true><<<dim3(4, 128), 256, 0, stream>>>(X, 512, ro, Wl1b, 512, 512, bl1b,
          nullptr, nullptr, nullptr, H1, nullptr, 512, nullptr, 0, nullptr);
      gemm_bt<2, false><<<dim3(4, 128), 256, 0, stream>>>(H1, 512, 0, Wl2b, 512, 512, bl2b,
          nullptr, Wlob, pred1 + ro, nullptr, nullptr, 512, nullptr, 0, nullptr);
    }
    for (int q = 0; q < 4; q++) {
      const size_t ro = (size_t)q * 16384;
      gemm_bt<4, false><<<dim3(4, 128), 256, 0, stream>>>(Mb, 512, ro, Wl1b, 512, 512, bl1b,
          nullptr, nullptr, pred1 + ro, H1, nullptr, 512, nullptr, 0, nullptr);
      gemm_bt<2, false><<<dim3(4, 128), 256, 0, stream>>>(H1, 512, 0, Wl2b, 512, 512, bl2b,
          nullptr, Wlob, rbuf + ro, nullptr, nullptr, 512, nullptr, 0, nullptr);
    }
  }

  // pred_adj[b,v,w] = rbuf[b,w,v]
  adj_out_kernel<<<256, 256, 0, stream>>>(rbuf, out);
  // x[b,v,:] = sum_w sigmoid(rbuf[b,w,v]) * M[b,:,v,w]
  msum_kernel<<<1024, 512, 0, stream>>>(rbuf, Mb, xb);
  // GRU gates
  gemm_bt<3, false><<<dim3(12, 8), 256, 0, stream>>>(xb, 512, 0, Wihb, 512, 512, bihb,
      nullptr, nullptr, nullptr, nullptr, gi, 1536, nullptr, 0, nullptr);
  gemm_bt<3, false><<<dim3(12, 8), 256, 0, stream>>>(nfb, 512, 0, Whhb, 512, 512, bhhb,
      nullptr, nullptr, nullptr, nullptr, gh, 1536, nullptr, 0, nullptr);
  gru_kernel<<<2048, 256, 0, stream>>>(gi, gh, nfb, hn);
  readout_kernel<<<1024, 256, 0, stream>>>(hn, Wr1b, br1b, Wr2b, br2b, out);
}